// Round 3
// baseline (1099.088 us; speedup 1.0000x reference)
//
#include <hip/hip_runtime.h>
#include <stdint.h>

// HashGrid3D, round 3: fused level-rotation kernel.
// Block -> XCD via blockIdx&7 (MI355X round-robin dispatch). XCD w walks
// levels (2w + t) % 16 for t=0..15, so at any instant the 8 XCDs work on 8
// DISTINCT levels: each XCD's 4 MB L2 holds exactly one 4 MB table (the R2
// residency win) while outputs accumulate in registers and leave as one
// coalesced 128 B/thread nontemporal store (no workspace, no transpose).

constexpr int   LVL   = 16;
constexpr int   TBL   = 524288;          // 2^19 entries per level
constexpr uint32_t TMASK = 0x7FFFFu;     // T-1
constexpr uint32_t P2 = 2654435761u;
constexpr uint32_t P3 = 805459861u;
__constant__ int RESV[LVL] = {16, 20, 25, 32, 40, 51, 64, 81,
                              102, 128, 161, 203, 256, 323, 406, 512};

typedef float v2f __attribute__((ext_vector_type(2)));
typedef float v4f __attribute__((ext_vector_type(4)));

__device__ __forceinline__ v2f hg_eval(const float2* __restrict__ tbl, int N,
                                       float x, float y, float z)
{
    float Nf = (float)N;
    float sx = x * Nf, sy = y * Nf, sz = z * Nf;
    float fx = floorf(sx), fy = floorf(sy), fz = floorf(sz);
    float tx = sx - fx, ty = sy - fy, tz = sz - fz;
    int ix = (int)fx, iy = (int)fy, iz = (int)fz;

    int ix0 = (ix >= N) ? ix - N : ix;
    int iy0 = (iy >= N) ? iy - N : iy;
    int iz0 = (iz >= N) ? iz - N : iz;
    int ix1 = ix + 1; ix1 = (ix1 >= N) ? ix1 - N : ix1;
    int iy1 = iy + 1; iy1 = (iy1 >= N) ? iy1 - N : iy1;
    int iz1 = iz + 1; iz1 = (iz1 >= N) ? iz1 - N : iz1;

    uint32_t hx0 = (uint32_t)ix0;
    uint32_t hx1 = (uint32_t)ix1;
    uint32_t hy0 = (uint32_t)iy0 * P2;
    uint32_t hy1 = (uint32_t)iy1 * P2;
    uint32_t hz0 = (uint32_t)iz0 * P3;
    uint32_t hz1 = (uint32_t)iz1 * P3;

    float2 g000 = tbl[(hx0 ^ hy0 ^ hz0) & TMASK];
    float2 g100 = tbl[(hx1 ^ hy0 ^ hz0) & TMASK];
    float2 g010 = tbl[(hx0 ^ hy1 ^ hz0) & TMASK];
    float2 g110 = tbl[(hx1 ^ hy1 ^ hz0) & TMASK];
    float2 g001 = tbl[(hx0 ^ hy0 ^ hz1) & TMASK];
    float2 g101 = tbl[(hx1 ^ hy0 ^ hz1) & TMASK];
    float2 g011 = tbl[(hx0 ^ hy1 ^ hz1) & TMASK];
    float2 g111 = tbl[(hx1 ^ hy1 ^ hz1) & TMASK];

    float wx1 = tx, wx0 = 1.0f - tx;
    float wy1 = ty, wy0 = 1.0f - ty;
    float wz1 = tz, wz0 = 1.0f - tz;
    float wz0y0 = wy0 * wz0, wz0y1 = wy1 * wz0;
    float wz1y0 = wy0 * wz1, wz1y1 = wy1 * wz1;
    float w000 = wx0 * wz0y0, w100 = wx1 * wz0y0;
    float w010 = wx0 * wz0y1, w110 = wx1 * wz0y1;
    float w001 = wx0 * wz1y0, w101 = wx1 * wz1y0;
    float w011 = wx0 * wz1y1, w111 = wx1 * wz1y1;

    v2f r;
    r.x = w000 * g000.x + w100 * g100.x + w010 * g010.x + w110 * g110.x
        + w001 * g001.x + w101 * g101.x + w011 * g011.x + w111 * g111.x;
    r.y = w000 * g000.y + w100 * g100.y + w010 * g010.y + w110 * g110.y
        + w001 * g001.y + w101 * g101.y + w011 * g011.y + w111 * g111.y;
    return r;
}

__global__ __launch_bounds__(256)
void hg_rot_kernel(const float* __restrict__ xyt,
                   const float* __restrict__ tables,
                   float* __restrict__ out, int n)
{
    int p = blockIdx.x * 256 + threadIdx.x;
    if (p >= n) return;

    // XCD id under round-robin dispatch; start offset spreads the 8 XCDs
    // over 8 distinct levels at every rotation step (2w+t all distinct mod 16).
    int base = (blockIdx.x & 7) * 2;

    float x = xyt[3 * p + 0];
    float y = xyt[3 * p + 1];
    float z = xyt[3 * p + 2];

    float outv[2 * LVL];

    for (int t = 0; t < LVL; ++t) {
        int l = (base + t) & 15;                       // wave-uniform
        const float2* __restrict__ tbl =
            (const float2*)tables + (size_t)l * TBL;
        v2f r = hg_eval(tbl, RESV[l], x, y, z);
        outv[2 * l + 0] = r.x;
        outv[2 * l + 1] = r.y;
    }

    // one coalesced 128 B/thread store; nontemporal so the output stream
    // doesn't evict the L2-resident table
    v4f* o = (v4f*)(out + (size_t)p * 32);
    const v4f* src = (const v4f*)outv;
    #pragma unroll
    for (int i = 0; i < 8; ++i)
        __builtin_nontemporal_store(src[i], o + i);
}

extern "C" void kernel_launch(void* const* d_in, const int* in_sizes, int n_in,
                              void* d_out, int out_size, void* d_ws, size_t ws_size,
                              hipStream_t stream) {
    const float* xyt    = (const float*)d_in[0];   // (n, 3) f32
    const float* tables = (const float*)d_in[1];   // (16, 524288, 2) f32
    float* out = (float*)d_out;                    // (n, 32) f32
    int n = in_sizes[0] / 3;
    int blocks = (n + 255) / 256;
    hg_rot_kernel<<<blocks, 256, 0, stream>>>(xyt, tables, out, n);
}

// Round 4
// 901.128 us; speedup vs baseline: 1.2197x; 1.2197x over previous
//
#include <hip/hip_runtime.h>
#include <stdint.h>

// HashGrid3D, round 4: R2's phase-pinned level kernel (measured 363 us,
// FETCH 241 MB) + cleaned-up transpose (plain cached loads -- the nt
// load path in R2 ran at 0.9 TB/s, 6x over roofline).
//
// Stage 1: block = (level, 256-point chunk). xcd = blockIdx&7 (round-robin
//   dispatch); XCD w serves level w in phase 0, level 15-w in phase 1, so
//   each XCD's 4 MB L2 holds exactly one 4 MB table at a time. Lesson from
//   R3: the level MUST be fixed for a block's lifetime -- rotation schemes
//   desynchronize and thrash (R3: FETCH 3 GB).
// Stage 2: transpose ws[16][n][2] -> out[n][32]. Intermediate is read-once,
//   plain loads, nt final stores.

constexpr int   LVL   = 16;
constexpr int   TBL   = 524288;          // 2^19 entries per level
constexpr uint32_t TMASK = 0x7FFFFu;
constexpr uint32_t P2 = 2654435761u;
constexpr uint32_t P3 = 805459861u;
constexpr int RESV[LVL] = {16, 20, 25, 32, 40, 51, 64, 81,
                           102, 128, 161, 203, 256, 323, 406, 512};

typedef float v2f __attribute__((ext_vector_type(2)));
typedef float v4f __attribute__((ext_vector_type(4)));

__device__ __forceinline__ v2f hg_eval(const float2* __restrict__ tbl, int N,
                                       float x, float y, float z)
{
    float Nf = (float)N;
    float sx = x * Nf, sy = y * Nf, sz = z * Nf;
    float fx = floorf(sx), fy = floorf(sy), fz = floorf(sz);
    float tx = sx - fx, ty = sy - fy, tz = sz - fz;
    int ix = (int)fx, iy = (int)fy, iz = (int)fz;

    int ix0 = (ix >= N) ? ix - N : ix;
    int iy0 = (iy >= N) ? iy - N : iy;
    int iz0 = (iz >= N) ? iz - N : iz;
    int ix1 = ix + 1; ix1 = (ix1 >= N) ? ix1 - N : ix1;
    int iy1 = iy + 1; iy1 = (iy1 >= N) ? iy1 - N : iy1;
    int iz1 = iz + 1; iz1 = (iz1 >= N) ? iz1 - N : iz1;

    uint32_t hx0 = (uint32_t)ix0;
    uint32_t hx1 = (uint32_t)ix1;
    uint32_t hy0 = (uint32_t)iy0 * P2;
    uint32_t hy1 = (uint32_t)iy1 * P2;
    uint32_t hz0 = (uint32_t)iz0 * P3;
    uint32_t hz1 = (uint32_t)iz1 * P3;

    float2 g000 = tbl[(hx0 ^ hy0 ^ hz0) & TMASK];
    float2 g100 = tbl[(hx1 ^ hy0 ^ hz0) & TMASK];
    float2 g010 = tbl[(hx0 ^ hy1 ^ hz0) & TMASK];
    float2 g110 = tbl[(hx1 ^ hy1 ^ hz0) & TMASK];
    float2 g001 = tbl[(hx0 ^ hy0 ^ hz1) & TMASK];
    float2 g101 = tbl[(hx1 ^ hy0 ^ hz1) & TMASK];
    float2 g011 = tbl[(hx0 ^ hy1 ^ hz1) & TMASK];
    float2 g111 = tbl[(hx1 ^ hy1 ^ hz1) & TMASK];

    float wx1 = tx, wx0 = 1.0f - tx;
    float wy1 = ty, wy0 = 1.0f - ty;
    float wz1 = tz, wz0 = 1.0f - tz;
    float wz0y0 = wy0 * wz0, wz0y1 = wy1 * wz0;
    float wz1y0 = wy0 * wz1, wz1y1 = wy1 * wz1;
    float w000 = wx0 * wz0y0, w100 = wx1 * wz0y0;
    float w010 = wx0 * wz0y1, w110 = wx1 * wz0y1;
    float w001 = wx0 * wz1y0, w101 = wx1 * wz1y0;
    float w011 = wx0 * wz1y1, w111 = wx1 * wz1y1;

    v2f r;
    r.x = w000 * g000.x + w100 * g100.x + w010 * g010.x + w110 * g110.x
        + w001 * g001.x + w101 * g101.x + w011 * g011.x + w111 * g111.x;
    r.y = w000 * g000.y + w100 * g100.y + w010 * g010.y + w110 * g110.y
        + w001 * g001.y + w101 * g101.y + w011 * g011.y + w111 * g111.y;
    return r;
}

// ---- stage 1: identical structure to R2 (measured 363 us) ----
__global__ __launch_bounds__(256)
void hg_level_kernel(const float* __restrict__ xyt,
                     const float* __restrict__ tables,
                     float* __restrict__ out_t, int n, int BPL)
{
    int b = blockIdx.x;
    int half = 8 * BPL;
    int phase = b / half;
    int slot  = b - phase * half;
    int xcd   = slot & 7;
    int chunk = slot >> 3;
    int level = (phase == 0) ? xcd : (15 - xcd);

    int p = chunk * 256 + threadIdx.x;
    if (p >= n) return;

    float x = xyt[3 * p + 0];
    float y = xyt[3 * p + 1];
    float z = xyt[3 * p + 2];

    const float2* __restrict__ tbl = (const float2*)tables + (size_t)level * TBL;
    v2f r = hg_eval(tbl, RESV[level], x, y, z);

    // nt store: protects the L2-resident table from the output stream
    v2f* dst = (v2f*)out_t + (size_t)level * n + p;
    __builtin_nontemporal_store(r, dst);
}

// ---- stage 2: transpose ws[16][n][2] -> out[n][32] ----
// 2 points per thread; plain cached loads (read-once data, but the cached
// path is the fast path); nt final stores.
__global__ __launch_bounds__(256)
void hg_transpose_kernel(const float* __restrict__ out_t,
                         float* __restrict__ out, int n)
{
    int t = blockIdx.x * 256 + threadIdx.x;
    int p0 = t * 2;
    if (p0 >= n) return;

    float2 a[LVL], b[LVL];
    const float2* src = (const float2*)out_t;
    #pragma unroll
    for (int l = 0; l < LVL; ++l) {
        const float2* row = src + (size_t)l * n + p0;
        a[l] = row[0];
        b[l] = row[1];
    }

    v4f* o0 = (v4f*)(out + (size_t)p0 * 32);
    v4f* o1 = (v4f*)(out + (size_t)(p0 + 1) * 32);
    const v4f* va = (const v4f*)a;
    const v4f* vb = (const v4f*)b;
    #pragma unroll
    for (int i = 0; i < 8; ++i) {
        __builtin_nontemporal_store(va[i], o0 + i);
        __builtin_nontemporal_store(vb[i], o1 + i);
    }
}

// ---- fallback if ws too small: round-1 monolithic (677 us measured) ----
__global__ __launch_bounds__(256)
void hg_mono_kernel(const float* __restrict__ xyt,
                    const float* __restrict__ tables,
                    float* __restrict__ out, int n)
{
    int p = blockIdx.x * 256 + threadIdx.x;
    if (p >= n) return;

    float x = xyt[3 * p + 0];
    float y = xyt[3 * p + 1];
    float z = xyt[3 * p + 2];

    float outv[2 * LVL];
    #pragma unroll
    for (int l = 0; l < LVL; ++l) {
        const float2* __restrict__ tbl = (const float2*)tables + (size_t)l * TBL;
        v2f r = hg_eval(tbl, RESV[l], x, y, z);
        outv[2 * l + 0] = r.x;
        outv[2 * l + 1] = r.y;
    }
    float4* o = (float4*)(out + (size_t)p * 32);
    #pragma unroll
    for (int i = 0; i < 8; ++i)
        o[i] = ((const float4*)outv)[i];
}

extern "C" void kernel_launch(void* const* d_in, const int* in_sizes, int n_in,
                              void* d_out, int out_size, void* d_ws, size_t ws_size,
                              hipStream_t stream) {
    const float* xyt    = (const float*)d_in[0];   // (n, 3) f32
    const float* tables = (const float*)d_in[1];   // (16, 524288, 2) f32
    float* out = (float*)d_out;                    // (n, 32) f32
    int n = in_sizes[0] / 3;

    size_t ws_needed = (size_t)LVL * (size_t)n * 2 * sizeof(float);
    if (ws_size >= ws_needed && (n % 512) == 0) {
        float* out_t = (float*)d_ws;
        int BPL = (n + 255) / 256;             // blocks per level
        int grid = 16 * BPL;                   // 2 phases x 8 xcd x BPL
        hg_level_kernel<<<grid, 256, 0, stream>>>(xyt, tables, out_t, n, BPL);
        int tblocks = (n / 2 + 255) / 256;
        hg_transpose_kernel<<<tblocks, 256, 0, stream>>>(out_t, out, n);
    } else {
        int blocks = (n + 255) / 256;
        hg_mono_kernel<<<blocks, 256, 0, stream>>>(xyt, tables, out, n);
    }
}